// Round 8
// baseline (108.515 us; speedup 1.0000x reference)
//
#include <hip/hip_runtime.h>
#include <hip/hip_bf16.h>

#define IN_DIMS  8192
#define OUT_DIMS 8192
#define NLAB     63
#define KS       8                    // split-K factor
#define KCH      (IN_DIMS / KS)       // 1024 K per workgroup
#define BK       32                   // K per tile (= MFMA K)
#define NT       (KCH / BK)           // 32 tiles
#define BN       64                   // W rows (N) per workgroup (16 per wave)

#define WBUF     2048                 // per-wave W tile: 16 rows x 128B
#define BUFB     (4 * WBUF)           // per-buffer (4 waves)
#define NBUF     4                    // 32KB total static LDS

typedef short  s16x8 __attribute__((ext_vector_type(8)));
typedef float  f32x4 __attribute__((ext_vector_type(4)));
typedef unsigned int u32;

__device__ __forceinline__ void gload16(const void* g, void* l) {
    __builtin_amdgcn_global_load_lds(
        (const __attribute__((address_space(1))) u32*)g,
        (__attribute__((address_space(3))) u32*)l, 16, 0, 0);
}

// ---- bf16 RNE pack helpers ----
__device__ __forceinline__ unsigned int rne2(float a, float b) {
    unsigned int ua = __float_as_uint(a), ub = __float_as_uint(b);
    ua += 0x7FFFu + ((ua >> 16) & 1u);
    ub += 0x7FFFu + ((ub >> 16) & 1u);
    return (ua >> 16) | (ub & 0xFFFF0000u);
}

// packed cvt: v_cvt_pk_bf16_f32 (RNE), 4 instrs per 8 floats
__device__ __forceinline__ s16x8 cvt8(float4 a, float4 b) {
    union { __hip_bfloat162 h[4]; s16x8 v; } u;
    u.h[0] = __float22bfloat162_rn(make_float2(a.x, a.y));
    u.h[1] = __float22bfloat162_rn(make_float2(a.z, a.w));
    u.h[2] = __float22bfloat162_rn(make_float2(b.x, b.y));
    u.h[3] = __float22bfloat162_rn(make_float2(b.z, b.w));
    return u.v;
}

// ---- kernel 1: Label f32 (63x8192) -> bf16 A (64x8192, row 63 zero) ----
__global__ __launch_bounds__(256) void k_prep(const float* __restrict__ L,
                                              unsigned short* __restrict__ A) {
    int e0 = (blockIdx.x * 256 + threadIdx.x) * 4;
    if (e0 >= 64 * IN_DIMS) return;
    float4 v = make_float4(0.f, 0.f, 0.f, 0.f);
    if (e0 < NLAB * IN_DIMS) v = *(const float4*)(L + e0);
    uint2 o;
    o.x = rne2(v.x, v.y);
    o.y = rne2(v.z, v.w);
    *(uint2*)(A + e0) = o;
}

// ---- kernel 2: BARRIER-FREE split-K MFMA GEMM ----
// W: per-wave-PRIVATE LDS staging (no cross-wave sharing -> no s_barrier),
//    NBUF=4 ring, pre-swizzled source so ds_read_b128 is conflict-free.
// A: registers, depth-2 named sets (L2-resident source).
// Per tile per wave: 2 W-DMAs + 4 A-loads = 6 vm ops in pinned order;
// s_waitcnt vmcnt(12) == exactly 2 tiles in flight, never drained to 0.
__global__ __launch_bounds__(256, 4) void k_gemm(const float* __restrict__ W,
                                                 const unsigned short* __restrict__ A,
                                                 float* __restrict__ Xp) {
    __shared__ char lds[NBUF * BUFB];
    const int nblk = blockIdx.x & 127;   // N tile (64 W-rows)
    const int kspl = blockIdx.x >> 7;    // K split
    const int w    = threadIdx.x >> 6;   // wave 0..3
    const int l    = threadIdx.x & 63;
    const int r    = l & 15;             // frag row-in-16
    const int g    = l >> 4;             // frag k-group

    const int  n0    = nblk * BN + w * 16;   // this wave's first W row
    const long kbase = (long)kspl * KCH;

    // W staging geometry: instr i covers rows i*8..i*8+7, 128B each
    const int srow = l >> 3;             // row-in-8
    const int sslt = (l & 7) ^ (l >> 3); // pre-swizzled 16B slot (row&7 == l>>3)

    auto stageW = [&](int tt, int bidx) {
        const long k0 = kbase + (long)tt * BK;
        char* buf = lds + bidx * BUFB + w * WBUF;
        #pragma unroll
        for (int i = 0; i < 2; ++i) {
            int row = i * 8 + srow;
            gload16(W + (long)(n0 + row) * IN_DIMS + k0 + sslt * 4,
                    buf + i * 1024 + l * 16);
        }
    };

    const unsigned short* ap = A + (long)r * IN_DIMS + kbase + g * 8;
    auto loadA = [&](int tt, s16x8* dst) {
        const unsigned short* p = ap + (long)tt * BK;
        dst[0] = *(const s16x8*)(p);
        dst[1] = *(const s16x8*)(p + 16L * IN_DIMS);
        dst[2] = *(const s16x8*)(p + 32L * IN_DIMS);
        dst[3] = *(const s16x8*)(p + 48L * IN_DIMS);
    };

    f32x4 acc0 = {0,0,0,0}, acc1 = {0,0,0,0}, acc2 = {0,0,0,0}, acc3 = {0,0,0,0};
    s16x8 aF[2][4];                      // depth-2 A sets (const-indexed post-unroll)

    // prologue, queue order: W(0) A(0) W(1) A(1)  -> 12 outstanding
    stageW(0, 0);
    loadA(0, aF[0]);
    stageW(1, 1);
    loadA(1, aF[1]);

    const int s0 = (g * 2) ^ (r & 7);    // W LDS slot for this lane's k-slice

    for (int ob = 0; ob < NT; ob += 4) {
        #pragma unroll
        for (int j = 0; j < 4; ++j) {
            const int t  = ob + j;
            const int tn = (t + 2 < NT) ? (t + 2) : 0;   // dummy refetch at tail
            stageW(tn, (t + 2) & 3);
            // oldest 6 (tile t: 2 W-DMA + 4 A-loads) retired; 2 tiles in flight
            asm volatile("s_waitcnt vmcnt(12)" ::: "memory");
            __builtin_amdgcn_sched_barrier(0);

            const float* ldsW = (const float*)(lds + (t & 3) * BUFB + w * WBUF);
            float4 w0 = *(const float4*)(ldsW + r * 32 + s0 * 4);
            float4 w1 = *(const float4*)(ldsW + r * 32 + (s0 ^ 1) * 4);
            s16x8 bw = cvt8(w0, w1);     // W[n0+r][k = g*8 .. g*8+7]
            acc0 = __builtin_amdgcn_mfma_f32_16x16x32_bf16(aF[j & 1][0], bw, acc0, 0, 0, 0);
            acc1 = __builtin_amdgcn_mfma_f32_16x16x32_bf16(aF[j & 1][1], bw, acc1, 0, 0, 0);
            acc2 = __builtin_amdgcn_mfma_f32_16x16x32_bf16(aF[j & 1][2], bw, acc2, 0, 0, 0);
            acc3 = __builtin_amdgcn_mfma_f32_16x16x32_bf16(aF[j & 1][3], bw, acc3, 0, 0, 0);
            loadA(tn, aF[j & 1]);        // refill consumed set for tile t+2
        }
    }

    // D layout: lane holds D[m = tb*16 + g*4 + q][n = n0 + r]
    float* xo = Xp + (long)kspl * BN * OUT_DIMS + n0 + r;
    #pragma unroll
    for (int q = 0; q < 4; ++q) {
        int m = g * 4 + q;
        xo[(long)(m     ) * OUT_DIMS] = acc0[q];
        xo[(long)(m + 16) * OUT_DIMS] = acc1[q];
        xo[(long)(m + 32) * OUT_DIMS] = acc2[q];
        xo[(long)(m + 48) * OUT_DIMS] = acc3[q];
    }
}

// ---- kernel 3: out(63x8192) = S(63x63) @ relu(sum_k Xp + b).view(8192,63)^T ----
__global__ __launch_bounds__(256) void k_out(const float* __restrict__ Xp,
                                             const float* __restrict__ S,
                                             const float* __restrict__ b,
                                             float* __restrict__ out) {
    __shared__ float sS[NLAB * NLAB];
    __shared__ float sml[32 * NLAB];
    const int k0 = blockIdx.x * 32;

    for (int p = threadIdx.x; p < NLAB * NLAB; p += 256) sS[p] = S[p];
    for (int p = threadIdx.x; p < 32 * NLAB; p += 256) {
        int gi = k0 * NLAB + p;          // flat index into X (row-major 63x8192)
        float v = 0.f;
        #pragma unroll
        for (int s = 0; s < KS; ++s)     // reduce split-K partials
            v += Xp[(long)s * 64 * OUT_DIMS + gi];
        v += b[gi & (OUT_DIMS - 1)];
        sml[p] = v > 0.f ? v : 0.f;
    }
    __syncthreads();

    for (int p = threadIdx.x; p < NLAB * 32; p += 256) {
        int i  = p >> 5;                 // output row
        int kk = p & 31;                 // output col within tile
        const float* srow = &sS[i * NLAB];
        const float* mrow = &sml[kk * NLAB];
        float sum = 0.f;
        #pragma unroll
        for (int j = 0; j < NLAB; ++j) sum += srow[j] * mrow[j];
        out[(long)i * OUT_DIMS + k0 + kk] = sum;
    }
}

extern "C" void kernel_launch(void* const* d_in, const int* in_sizes, int n_in,
                              void* d_out, int out_size, void* d_ws, size_t ws_size,
                              hipStream_t stream) {
    const float* Label = (const float*)d_in[0];   // 63x8192
    const float* S     = (const float*)d_in[1];   // 63x63
    const float* W     = (const float*)d_in[2];   // 8192x8192
    const float* b     = (const float*)d_in[3];   // 8192
    float* out = (float*)d_out;

    unsigned short* A  = (unsigned short*)d_ws;                      // 1 MB bf16 A
    float*          Xp = (float*)((char*)d_ws + 64 * IN_DIMS * 2);   // KS x 2 MB partials

    k_prep<<<dim3((64 * IN_DIMS / 4 + 255) / 256), dim3(256), 0, stream>>>(Label, A);
    k_gemm<<<dim3(128 * KS), dim3(256), 0, stream>>>(W, A, Xp);
    k_out <<<dim3(OUT_DIMS / 32), dim3(256), 0, stream>>>(Xp, S, b, out);
}